// Round 10
// baseline (38.356 us; speedup 1.0000x reference)
//
#include <hip/hip_runtime.h>

typedef unsigned int uint;
typedef unsigned char u8;

// Problem constants (from setup_inputs)
#define B_     2
#define C_     16
#define H_     66
#define W_     66
#define O_     64
#define CKK    144
#define NCH    36          // CKK/4
#define DIM    64          // output spatial
#define L_     4096        // DIM*DIM
#define N_     8192        // B_*L_
#define PLANE  524288      // N_*O_  (elements between (c,s) planes of rand_idx)
#define NB     32          // n per block (8192/256)
#define TSTR   1024        // u8 table row stride
#define TCOLS  1000

// Plane-major decomposition:
//   72 planes (c,s) x 2 halves (16 n) = 144 units.
//   wave wv: half h = wv&1 (n-offset h*16), planes p0..p0+8, p0 = 9*(wv>>1).
//   Each unit = 16 loads of 256 B CONSECUTIVE in memory (4 KB sequential run)
//   -> DRAM row-buffer locality, unlike the previous 72-plane stride pattern.
__launch_bounds__(1024)
__global__ void k_fused(const float* __restrict__ x,
                        const float* __restrict__ wgt,
                        const float* __restrict__ cbias,
                        const float* __restrict__ pmin,
                        const float* __restrict__ pmax,
                        const float* __restrict__ ptbl,
                        const int*   __restrict__ ridx,
                        float* __restrict__ out) {
    __shared__ __align__(16) u8 tbl[54 * TSTR]; // 55,296: row0=zeros, rows 1..53 = ptbl rows 8..60
    __shared__ uint2 s_w[NCH * O_];             // 18,432  [c][o] ternary masks
    __shared__ uint  s_xq[NB * NCH];            //  4,608  [n][c] packed Xq
    __shared__ short slab[16][16][66];          // 33,792  per-wave int16 partials (padded)
    __shared__ float s_bias[O_];                //     256
    // total 112,384 B -> 1 block/CU, 16 waves

    const int tid = threadIdx.x;
    const int wv  = tid >> 6;
    const int o   = tid & 63;
    const int h16 = (wv & 1) << 4;          // n-offset of this wave's half
    const int p0  = 9 * (wv >> 1);          // first plane of this wave
    const int nb0 = blockIdx.x * NB;

    const float mn = pmin[0];
    const float sc = pmax[0] - mn;

    const int* rbase = ridx + (nb0 + h16) * O_ + o;

    int idxA[16], idxB[16];
#define LOADU(BUF, J)                                                    \
    {                                                                    \
        const int* ptr = rbase + (p0 + (J)) * PLANE;                     \
        _Pragma("unroll")                                                \
        for (int k = 0; k < 16; ++k) BUF[k] = ptr[k * O_];               \
    }

    // issue first two units before staging (oldest in vmcnt queue)
    LOADU(idxA, 0)
    LOADU(idxB, 1)

    // ---- Phase 0a: zero u8 table row 0 ----
    if (tid < 64) {
        uint4 z; z.x = z.y = z.z = z.w = 0u;
        ((uint4*)tbl)[tid] = z;
    }
    // ---- Phase 0b: ptbl rows 8..60 -> u8 rows 1..53 (val = rint(v*255)) ----
    for (int q = tid; q < 53 * 250; q += 1024) {     // 250 float4 per source row
        int r = q / 250, k = q - r * 250;
        float4 v = *(const float4*)(ptbl + (8 + r) * TCOLS + k * 4);
        uint b0 = (uint)rintf(v.x * 255.f), b1 = (uint)rintf(v.y * 255.f);
        uint b2 = (uint)rintf(v.z * 255.f), b3 = (uint)rintf(v.w * 255.f);
        *(uint*)(tbl + (r + 1) * TSTR + k * 4) = b0 | (b1 << 8) | (b2 << 16) | (b3 << 24);
    }
    // ---- Phase 0c: ternary weight masks [c][o] as uint2 ----
    for (int q = tid; q < NCH * O_; q += 1024) {
        int c = q >> 6, oo = q & 63;
        float4 v = *(const float4*)(wgt + oo * CKK + c * 4);
        uint pm = 0, nm = 0;
        if (v.x > 0.0f) pm |= 0x000000FFu; else if (v.x < 0.0f) nm |= 0x000000FFu;
        if (v.y > 0.0f) pm |= 0x0000FF00u; else if (v.y < 0.0f) nm |= 0x0000FF00u;
        if (v.z > 0.0f) pm |= 0x00FF0000u; else if (v.z < 0.0f) nm |= 0x00FF0000u;
        if (v.w > 0.0f) pm |= 0xFF000000u; else if (v.w < 0.0f) nm |= 0xFF000000u;
        s_w[q] = make_uint2(pm, nm);
    }
    // ---- Phase 0d: quantize this block's 32 patches (32 n x 36 c = 1152 > 1024!) ----
    for (int i = tid; i < NB * NCH; i += 1024) {     // FIX R9: was if(tid<1152)
        int nl2 = i / NCH;
        int c2  = i - nl2 * NCH;
        int n2  = nb0 + nl2;
        int b2 = n2 >> 12, l2 = n2 & (L_ - 1);
        int h2 = l2 >> 6,  w2 = l2 & (DIM - 1);
        uint packed = 0;
#pragma unroll
        for (int k = 0; k < 4; ++k) {
            int j  = c2 * 4 + k;
            int ci = j / 9;
            int r2 = j - ci * 9;
            int kh = r2 / 3;
            int kw = r2 - kh * 3;
            float v = x[((b2 * C_ + ci) * H_ + (h2 + kh)) * W_ + (w2 + kw)];
            float t2 = (v - mn) / sc * 15.0f;              // jax f32 op order
            float q = fminf(fmaxf(rintf(t2), 0.0f), 15.0f);
            packed |= ((uint)q) << (8 * k);
        }
        s_xq[i] = packed;
    }
    // ---- Phase 0e: bias from wgt (threads 0..63, L2-hot) ----
    if (tid < O_) {
        int sw = 0;
        for (int j = 0; j < CKK; ++j) {
            float v = wgt[tid * CKK + j];
            sw += (v > 0.0f) - (v < 0.0f);
        }
        s_bias[tid] = mn * (float)sw + cbias[tid];
    }
    __syncthreads();

    // ---- main: 9 units, 2-deep ping-pong, sequential 4 KB runs per unit ----
    const u8* tb = tbl - 7 * TSTR;           // row=max(y,7): y<8 -> zero row
    int acc[16];
#pragma unroll
    for (int k = 0; k < 16; ++k) acc[k] = 0;

#define PROCU(BUF, J)                                                    \
    {                                                                    \
        const int p = p0 + (J);                                          \
        const uint2 mm = s_w[(p >> 1) * O_ + o];                         \
        const uint m = (p & 1) ? mm.y : mm.x;                            \
        const int sm = (p & 1) ? -1 : 0;                                 \
        _Pragma("unroll")                                                \
        for (int k = 0; k < 16; ++k) {                                   \
            uint xv = s_xq[(h16 + k) * NCH + (p >> 1)];                  \
            uint y = ((xv & m) * 0x01010101u) >> 24;                     \
            uint row = y < 7u ? 7u : y;                                  \
            int v = (int)tb[(row << 10) + (uint)BUF[k]];                 \
            acc[k] += (v ^ sm) - sm;                                     \
        }                                                                \
    }

    PROCU(idxA, 0) LOADU(idxA, 2)
    PROCU(idxB, 1) LOADU(idxB, 3)
    PROCU(idxA, 2) LOADU(idxA, 4)
    PROCU(idxB, 3) LOADU(idxB, 5)
    PROCU(idxA, 4) LOADU(idxA, 6)
    PROCU(idxB, 5) LOADU(idxB, 7)
    PROCU(idxA, 6) LOADU(idxA, 8)
    PROCU(idxB, 7)
    PROCU(idxA, 8)

    // ---- write per-wave partials (int16, wave-private slab, 2-way free) ----
#pragma unroll
    for (int k = 0; k < 16; ++k) slab[wv][k][o] = (short)acc[k];
    __syncthreads();

    // ---- reduce 8 slabs per half + epilogue ----
    // thread t: o = t>>4, n = t&15 (half 0 via even waves, half 1 via odd)
    const int ro = tid >> 4;
    const int rn = tid & 15;
    int s0 = 0, s1 = 0;
#pragma unroll
    for (int w2 = 0; w2 < 8; ++w2) {
        s0 += slab[2 * w2][rn][ro];      // even waves: n = rn
        s1 += slab[2 * w2 + 1][rn][ro];  // odd  waves: n = rn + 16
    }
    const float k255 = sc * (1.0f / 255.0f);
    const float bo   = s_bias[ro];
    const int   b    = nb0 >> 12;
    const int   lb   = nb0 & (L_ - 1);
    out[(b * O_ + ro) * L_ + lb + rn]      = (float)s0 * k255 + bo;
    out[(b * O_ + ro) * L_ + lb + rn + 16] = (float)s1 * k255 + bo;
}

extern "C" void kernel_launch(void* const* d_in, const int* in_sizes, int n_in,
                              void* d_out, int out_size, void* d_ws, size_t ws_size,
                              hipStream_t stream) {
    const float* x     = (const float*)d_in[0];
    const float* wgt   = (const float*)d_in[1];
    const float* cbias = (const float*)d_in[2];
    const float* pmin  = (const float*)d_in[3];
    const float* pmax  = (const float*)d_in[4];
    const float* ptbl  = (const float*)d_in[5];
    const int*   ridx  = (const int*)d_in[6];
    float* out = (float*)d_out;

    k_fused<<<256, 1024, 0, stream>>>(x, wgt, cbias, pmin, pmax, ptbl, ridx, out);
}

// Round 11
// 34.843 us; speedup vs baseline: 1.1008x; 1.1008x over previous
//
#include <hip/hip_runtime.h>

typedef unsigned int uint;

// Problem constants (from setup_inputs)
#define B_     2
#define C_     16
#define H_     66
#define W_     66
#define O_     64
#define CKK    144
#define NCH    36          // CKK/4
#define DIM    64          // output spatial
#define L_     4096        // DIM*DIM
#define N_     8192        // B_*L_
#define PLANE  524288      // N_*O_  (stride between (c,s) planes of rand_idx)
#define TROWS  61          // table rows 0..60 (0..7 zeroed: sign(Q)==0 there)
#define TCOLS  1000

typedef _Float16 h4 __attribute__((ext_vector_type(4)));

// ---- prefetch group: 4 chunks x 2 signs x 2 streams = 16 coalesced loads ----
__device__ __forceinline__ void loadg(int (&buf)[16],
                                      const int* __restrict__ rp0,
                                      const int* __restrict__ rp1, int c0) {
#pragma unroll
    for (int j = 0; j < 4; ++j) {
        int c = c0 + j;
        buf[4 * j + 0] = rp0[(2 * c)     * PLANE];
        buf[4 * j + 1] = rp0[(2 * c + 1) * PLANE];
        buf[4 * j + 2] = rp1[(2 * c)     * PLANE];
        buf[4 * j + 3] = rp1[(2 * c + 1) * PLANE];
    }
}

// ---- consume one group: dot4 masks + 4 unconditional LDS gathers per j ----
__device__ __forceinline__ void procg(const int (&buf)[16],
                                      const uint* __restrict__ xq0,
                                      const uint* __restrict__ xq1,
                                      const uint2* __restrict__ sw,
                                      const _Float16* __restrict__ tbl,
                                      int c0, int o,
                                      float& sum0, float& sum1) {
#pragma unroll
    for (int j = 0; j < 4; ++j) {
        int c = c0 + j;
        uint xv0 = xq0[c];                      // wave-uniform LDS broadcast
        uint xv1 = xq1[c];
        uint2 m  = sw[c * O_ + o];
        uint yp0 = ((xv0 & m.x) * 0x01010101u) >> 24;
        uint ym0 = ((xv0 & m.y) * 0x01010101u) >> 24;
        uint yp1 = ((xv1 & m.x) * 0x01010101u) >> 24;
        uint ym1 = ((xv1 & m.y) * 0x01010101u) >> 24;
        sum0 += (float)tbl[yp0 * TCOLS + buf[4 * j + 0]];
        sum0 -= (float)tbl[ym0 * TCOLS + buf[4 * j + 1]];
        sum1 += (float)tbl[yp1 * TCOLS + buf[4 * j + 2]];
        sum1 -= (float)tbl[ym1 * TCOLS + buf[4 * j + 3]];
    }
}

__launch_bounds__(1024)
__global__ void k_fused(const float* __restrict__ x,
                        const float* __restrict__ wgt,
                        const float* __restrict__ cbias,
                        const float* __restrict__ pmin,
                        const float* __restrict__ pmax,
                        const float* __restrict__ ptbl,
                        const int*   __restrict__ ridx,
                        float* __restrict__ out) {
    __shared__ __align__(16) _Float16 tbl[TROWS * TCOLS]; // 122,000 B
    __shared__ uint2 s_w[NCH * O_];                       //  18,432 B
    __shared__ float s_bias[O_];                          //     256 B
    __shared__ uint  s_xq[2][16 * NCH];                   //   4,608 B

    const int tid = threadIdx.x;
    const float mn = pmin[0];
    const float sc = pmax[0] - mn;

    // ---- Phase 0a: zero rows 0..7 (16,000 B) as uint4 ----
    {
        uint4 z; z.x = z.y = z.z = z.w = 0u;
        uint4* zp = (uint4*)tbl;
        for (int p = tid; p < 1000; p += 1024) zp[p] = z;
    }
    // ---- Phase 0b: rows 8..60 -> fp16 LDS, float4-vectorized ----
    {
        const float4* src = (const float4*)(ptbl + 8 * TCOLS); // 16B aligned
        h4* dst = (h4*)(tbl + 8 * TCOLS);                      // 16B aligned
        for (int p = tid; p < (53 * TCOLS) / 4; p += 1024) {   // 13,250
            float4 v = src[p];
            h4 h = { (_Float16)v.x, (_Float16)v.y, (_Float16)v.z, (_Float16)v.w };
            dst[p] = h;
        }
    }
    // ---- Phase 0c: ternary weight byte-masks (float4 loads) ----
    for (int p = tid; p < NCH * O_; p += 1024) {               // 2,304
        int c = p >> 6, oo = p & 63;
        float4 v = *(const float4*)(wgt + oo * CKK + c * 4);   // 16B aligned
        uint pm = 0, nm = 0;
        if (v.x > 0.0f) pm |= 0x000000FFu; else if (v.x < 0.0f) nm |= 0x000000FFu;
        if (v.y > 0.0f) pm |= 0x0000FF00u; else if (v.y < 0.0f) nm |= 0x0000FF00u;
        if (v.z > 0.0f) pm |= 0x00FF0000u; else if (v.z < 0.0f) nm |= 0x00FF0000u;
        if (v.w > 0.0f) pm |= 0xFF000000u; else if (v.w < 0.0f) nm |= 0xFF000000u;
        s_w[p] = make_uint2(pm, nm);
    }
    // ---- Phase 0d: quantize both tiles' 32 patches into s_xq ----
    for (int i = tid; i < 2 * 16 * NCH; i += 1024) {           // 1,152
        int t  = i / (16 * NCH);
        int r  = i - t * (16 * NCH);
        int nl2 = r / NCH;
        int c2  = r - nl2 * NCH;
        int n2  = (blockIdx.x + t * 256) * 16 + nl2;
        int b2 = n2 >> 12, l2 = n2 & (L_ - 1);
        int h2 = l2 >> 6,  w2 = l2 & (DIM - 1);
        uint packed = 0;
#pragma unroll
        for (int k = 0; k < 4; ++k) {
            int j  = c2 * 4 + k;
            int ci = j / 9;
            int r2 = j - ci * 9;
            int kh = r2 / 3;
            int kw = r2 - kh * 3;
            float v = x[((b2 * C_ + ci) * H_ + (h2 + kh)) * W_ + (w2 + kw)];
            float t2 = (v - mn) / sc * 15.0f;                  // jax f32 op order
            float q = fminf(fmaxf(rintf(t2), 0.0f), 15.0f);
            packed |= ((uint)q) << (8 * k);
        }
        s_xq[t][r] = packed;
    }

    // ---- main: dual-stream, barrier-free, 2-deep prefetch pipeline ----
    const int o  = tid & 63;
    const int nl = tid >> 6;                   // 0..15
    const int n0 = blockIdx.x * 16 + nl;       // tile bid      (batch 0)
    const int n1 = n0 + 4096;                  // tile bid+256  (batch 1)
    const int* rp0 = ridx + n0 * O_ + o;
    const int* rp1 = ridx + n1 * O_ + o;

    int A[16], Bb[16];
    loadg(A,  rp0, rp1, 0);                    // in flight across the barrier
    loadg(Bb, rp0, rp1, 4);

    // bias from masks (needs s_w): compute after staging, before barrier use
    __syncthreads();
    if (tid < O_) {
        int sw2 = 0;
        for (int c = 0; c < NCH; ++c) {
            uint2 m = s_w[c * O_ + tid];
            sw2 += (__popc(m.x) >> 3) - (__popc(m.y) >> 3);
        }
        s_bias[tid] = mn * (float)sw2 + cbias[tid];
    }
    __syncthreads();

    const uint* xq0 = &s_xq[0][nl * NCH];
    const uint* xq1 = &s_xq[1][nl * NCH];
    const float bo  = s_bias[o];
    float sum0 = 0.0f, sum1 = 0.0f;

    procg(A,  xq0, xq1, s_w, tbl,  0, o, sum0, sum1); loadg(A,  rp0, rp1,  8);
    procg(Bb, xq0, xq1, s_w, tbl,  4, o, sum0, sum1); loadg(Bb, rp0, rp1, 12);
    procg(A,  xq0, xq1, s_w, tbl,  8, o, sum0, sum1); loadg(A,  rp0, rp1, 16);
    procg(Bb, xq0, xq1, s_w, tbl, 12, o, sum0, sum1); loadg(Bb, rp0, rp1, 20);
    procg(A,  xq0, xq1, s_w, tbl, 16, o, sum0, sum1); loadg(A,  rp0, rp1, 24);
    procg(Bb, xq0, xq1, s_w, tbl, 20, o, sum0, sum1); loadg(Bb, rp0, rp1, 28);
    procg(A,  xq0, xq1, s_w, tbl, 24, o, sum0, sum1); loadg(A,  rp0, rp1, 32);
    procg(Bb, xq0, xq1, s_w, tbl, 28, o, sum0, sum1);
    procg(A,  xq0, xq1, s_w, tbl, 32, o, sum0, sum1);

    // out[b][o][l]: n0 -> b=0,l=n0 ; n1 -> b=1,l=n1-4096
    out[o * L_ + n0]                       = sum0 * sc + bo;
    out[(O_ + o) * L_ + (n1 & (L_ - 1))]   = sum1 * sc + bo;
}

extern "C" void kernel_launch(void* const* d_in, const int* in_sizes, int n_in,
                              void* d_out, int out_size, void* d_ws, size_t ws_size,
                              hipStream_t stream) {
    const float* x     = (const float*)d_in[0];
    const float* wgt   = (const float*)d_in[1];
    const float* cbias = (const float*)d_in[2];
    const float* pmin  = (const float*)d_in[3];
    const float* pmax  = (const float*)d_in[4];
    const float* ptbl  = (const float*)d_in[5];
    const int*   ridx  = (const int*)d_in[6];
    float* out = (float*)d_out;

    k_fused<<<256, 1024, 0, stream>>>(x, wgt, cbias, pmin, pmax, ptbl, ridx, out);
}